// Round 2
// baseline (493.362 us; speedup 1.0000x reference)
//
#include <hip/hip_runtime.h>
#include <hip/hip_bf16.h>

// Problem: STN  B=16, H=W=256, C=32, FILTER=64 (f4=16, f2=32)
//
// Workspace layout (floats):
//   p1    : 16*127*127*16 = 4,129,024
//   p2    : 16* 62* 62*32 = 1,968,128
//   p3    : 16* 30* 30*32 =   460,800
//   theta : 16*6          =        96

#define P1_ELEMS 4129024
#define P2_ELEMS 1968128
#define P3_ELEMS 460800

// ---------------------------------------------------------------- conv+pool
// Unified template. Block = 256 thr = 4 waves; block tile = 4 pooled rows x
// 16 pooled cols = 8x32 conv pixels = 256 lanes, ONE conv pixel per lane,
// ALL F filters per lane (no cross-wave LDS read duplication — the previous
// version had every wave re-reading the same xt addresses for its filter
// slice; LDS bandwidth co-limited with VALU).
//
// LDS layout: channel-plane-major float4 planes, plane = [10][34] pixels,
// plane stride 341 float4 (341*16 B = 5456 B ≡ 20*4 B mod 128 B → the
// per-ch4 bank starts {0,20,8,28,16,4,24,12} are all distinct mod 32, so
// staging writes and compute reads are conflict-free). All tap/plane read
// offsets are compile-time ds_read immediates off a single per-lane vaddr.
//
// Weights are wave-uniform -> s_load, SGPR operand in v_fmac (1 SGPR/VALU op
// allowed). Pool+ReLU via __shfl_xor(1) / __shfl_xor(32); lanes with
// (lane&1)==0 && lane<32 write the 16-col pooled row.

template<int CH, int F, int IN_HW, int POOL_HW>
__global__ __launch_bounds__(256) void conv_pool_kernel(
    const float* __restrict__ in, const float* __restrict__ Wt,
    const float* __restrict__ bias, float* __restrict__ out)
{
    constexpr int PLANES = CH / 4;
    constexpr int LP     = (PLANES == 8) ? 3 : 2;
    constexpr int PSTR   = 341;                 // float4 per plane (10*34=340 +1)
    __shared__ float4 xt[PLANES * PSTR];        // CH=32: 43,648 B; CH=16: 21,824 B

    const int tid = threadIdx.x;
    const int b   = blockIdx.z;
    const int r0  = blockIdx.y * 8;             // conv/input row origin
    const int c0  = blockIdx.x * 32;            // conv/input col origin
    const float* ib = in + (size_t)b * (IN_HW * IN_HW * CH);

    // ---- stage 10x34 pixels x CH channels, plane-major ----
    for (int idx = tid; idx < 340 * PLANES; idx += 256) {
        const int ch4 = idx & (PLANES - 1);     // fastest -> coalesced global reads
        const int pix = idx >> LP;
        const int dr  = pix / 34;
        const int j   = pix - dr * 34;
        int r = r0 + dr; if (r > IN_HW - 1) r = IN_HW - 1;
        int c = c0 + j;  if (c > IN_HW - 1) c = IN_HW - 1;
        xt[ch4 * PSTR + pix] =
            *(const float4*)(ib + ((size_t)r * IN_HW + c) * CH + ch4 * 4);
    }
    __syncthreads();

    const int wv   = tid >> 6;
    const int lane = tid & 63;
    const int ccol = lane & 31;                         // conv col within tile
    const int px0  = (2 * wv + (lane >> 5)) * 34 + ccol; // conv pixel base in plane

    float4 acc[F / 4];
    #pragma unroll
    for (int q = 0; q < F / 4; ++q) acc[q] = *(const float4*)(bias + 4 * q);

    #pragma unroll 1
    for (int kh = 0; kh < 3; ++kh) {
      #pragma unroll 1
      for (int kw = 0; kw < 3; ++kw) {
        const float* wp = Wt + (kh * 3 + kw) * CH * F;   // uniform
        const int px = px0 + kh * 34 + kw;
        #pragma unroll
        for (int c4 = 0; c4 < PLANES; ++c4) {
            const float4 xv = xt[c4 * PSTR + px];        // 1 vaddr + imm offsets
            #pragma unroll
            for (int cc = 0; cc < 4; ++cc) {
                const float xc = (cc == 0) ? xv.x : (cc == 1) ? xv.y
                               : (cc == 2) ? xv.z : xv.w;
                const float* wr = wp + (4 * c4 + cc) * F;
                #pragma unroll
                for (int q = 0; q < F / 4; ++q) {
                    const float4 w4 = *(const float4*)(wr + 4 * q);  // s_load
                    acc[q].x += xc * w4.x; acc[q].y += xc * w4.y;
                    acc[q].z += xc * w4.z; acc[q].w += xc * w4.w;
                }
            }
        }
      }
    }

    // ---- 2x2 max-pool across lanes + ReLU ----
    #pragma unroll
    for (int q = 0; q < F / 4; ++q) {
        float4 v = acc[q];
        v.x = fmaxf(v.x, __shfl_xor(v.x, 1));
        v.y = fmaxf(v.y, __shfl_xor(v.y, 1));
        v.z = fmaxf(v.z, __shfl_xor(v.z, 1));
        v.w = fmaxf(v.w, __shfl_xor(v.w, 1));
        v.x = fmaxf(fmaxf(v.x, __shfl_xor(v.x, 32)), 0.0f);
        v.y = fmaxf(fmaxf(v.y, __shfl_xor(v.y, 32)), 0.0f);
        v.z = fmaxf(fmaxf(v.z, __shfl_xor(v.z, 32)), 0.0f);
        v.w = fmaxf(fmaxf(v.w, __shfl_xor(v.w, 32)), 0.0f);
        acc[q] = v;
    }

    const int pr = blockIdx.y * 4 + wv;
    const int pc = blockIdx.x * 16 + (ccol >> 1);
    if ((lane & 1) == 0 && lane < 32 && pr < POOL_HW && pc < POOL_HW) {
        float* dst = out + (((size_t)b * POOL_HW + pr) * POOL_HW + pc) * F;
        #pragma unroll
        for (int q = 0; q < F / 4; ++q) *(float4*)(dst + 4 * q) = acc[q];
    }
}

// ----------------------------------------------------------------- head
__global__ __launch_bounds__(256) void head_kernel(
    const float* __restrict__ p3,
    const float* __restrict__ D1, const float* __restrict__ db1,
    const float* __restrict__ D2, const float* __restrict__ db2,
    const float* __restrict__ D3, const float* __restrict__ db3,
    float* __restrict__ theta)
{
    __shared__ float red[8][32];
    __shared__ float hmean[32];
    __shared__ float h1[64];
    __shared__ float h2[32];

    const int b   = blockIdx.x;
    const int tid = threadIdx.x;
    const int c = tid & 31, r = tid >> 5;

    const float* p = p3 + (size_t)b * (900*32);
    float s = 0.0f;
    for (int i = r; i < 900; i += 8) s += p[i*32 + c];
    red[r][c] = s;
    __syncthreads();

    if (tid < 32) {
        float m = 0.0f;
        #pragma unroll
        for (int j = 0; j < 8; ++j) m += red[j][tid];
        hmean[tid] = m * (1.0f / 900.0f);
    }
    __syncthreads();

    if (tid < 64) {
        float a = db1[tid];
        #pragma unroll
        for (int k = 0; k < 32; ++k) a += hmean[k] * D1[k*64 + tid];
        h1[tid] = fmaxf(a, 0.0f);
    }
    __syncthreads();

    if (tid < 32) {
        float a = db2[tid];
        #pragma unroll
        for (int k = 0; k < 64; ++k) a += h1[k] * D2[k*32 + tid];
        h2[tid] = fmaxf(a, 0.0f);
    }
    __syncthreads();

    if (tid < 6) {
        float a = db3[tid];
        #pragma unroll
        for (int k = 0; k < 32; ++k) a += h2[k] * D3[k*6 + tid];
        theta[b*6 + tid] = a;
    }
}

// ----------------------------------------------------------------- sampler
__global__ __launch_bounds__(256) void sampler_kernel(
    const float* __restrict__ x, const float* __restrict__ theta,
    float* __restrict__ out)
{
    const int t  = blockIdx.x * 256 + threadIdx.x;
    const int c4 = t & 7;
    const int w  = (t >> 3) & 255;
    const int h  = (t >> 11) & 255;
    const int b  = t >> 19;

    const float* th = theta + b*6;
    const float gx = -1.0f + (float)w * (2.0f / 255.0f);
    const float gy = -1.0f + (float)h * (2.0f / 255.0f);
    const float xS = th[0]*gx + th[1]*gy + th[2];
    const float yS = th[3]*gx + th[4]*gy + th[5];
    const float xp = 0.5f * (xS + 1.0f) * 254.0f;
    const float yp = 0.5f * (yS + 1.0f) * 254.0f;

    int x0 = (int)floorf(xp), y0 = (int)floorf(yp);
    int x1 = x0 + 1,          y1 = y0 + 1;
    x0 = x0 < 0 ? 0 : (x0 > 255 ? 255 : x0);
    x1 = x1 < 0 ? 0 : (x1 > 255 ? 255 : x1);
    y0 = y0 < 0 ? 0 : (y0 > 255 ? 255 : y0);
    y1 = y1 < 0 ? 0 : (y1 > 255 ? 255 : y1);

    const float x0f = (float)x0, x1f = (float)x1;
    const float y0f = (float)y0, y1f = (float)y1;
    const float wa = (x1f - xp) * (y1f - yp);
    const float wb = (x1f - xp) * (yp - y0f);
    const float wc = (xp - x0f) * (y1f - yp);
    const float wd = (xp - x0f) * (yp - y0f);

    const float* xb = x + (size_t)b * (256*256*32) + c4*4;
    const float4 Ia = *(const float4*)(xb + ((size_t)y0*256 + x0)*32);
    const float4 Ib = *(const float4*)(xb + ((size_t)y1*256 + x0)*32);
    const float4 Ic = *(const float4*)(xb + ((size_t)y0*256 + x1)*32);
    const float4 Id = *(const float4*)(xb + ((size_t)y1*256 + x1)*32);

    float4 o;
    o.x = wa*Ia.x + wb*Ib.x + wc*Ic.x + wd*Id.x;
    o.y = wa*Ia.y + wb*Ib.y + wc*Ic.y + wd*Id.y;
    o.z = wa*Ia.z + wb*Ib.z + wc*Ic.z + wd*Id.z;
    o.w = wa*Ia.w + wb*Ib.w + wc*Ic.w + wd*Id.w;
    ((float4*)out)[t] = o;
}

// ----------------------------------------------------------------- launch
extern "C" void kernel_launch(void* const* d_in, const int* in_sizes, int n_in,
                              void* d_out, int out_size, void* d_ws, size_t ws_size,
                              hipStream_t stream) {
    const float* x   = (const float*)d_in[0];
    const float* W1  = (const float*)d_in[1];
    const float* b1  = (const float*)d_in[2];
    const float* W2  = (const float*)d_in[3];
    const float* b2  = (const float*)d_in[4];
    const float* W3  = (const float*)d_in[5];
    const float* b3  = (const float*)d_in[6];
    const float* D1  = (const float*)d_in[7];
    const float* db1 = (const float*)d_in[8];
    const float* D2  = (const float*)d_in[9];
    const float* db2 = (const float*)d_in[10];
    const float* D3  = (const float*)d_in[11];
    const float* db3 = (const float*)d_in[12];
    float* out = (float*)d_out;

    float* p1    = (float*)d_ws;
    float* p2    = p1 + P1_ELEMS;
    float* p3    = p2 + P2_ELEMS;
    float* theta = p3 + P3_ELEMS;

    conv_pool_kernel<32, 16, 256, 127><<<dim3(8, 32, 16), 256, 0, stream>>>(x,  W1, b1, p1);
    conv_pool_kernel<16, 32, 127,  62><<<dim3(4, 16, 16), 256, 0, stream>>>(p1, W2, b2, p2);
    conv_pool_kernel<32, 32,  62,  30><<<dim3(2, 8, 16),  256, 0, stream>>>(p2, W3, b3, p3);
    head_kernel      <<<dim3(16),    256, 0, stream>>>(p3, D1, db1, D2, db2, D3, db3, theta);
    sampler_kernel   <<<dim3(32768), 256, 0, stream>>>(x, theta, out);
}